// Round 12
// baseline (98.399 us; speedup 1.0000x reference)
//
#include <hip/hip_runtime.h>
#include <stdint.h>

// Problem constants
#define CH 8      // heads
#define CDH 64    // dim head
#define CB 2      // batch
#define CN 2048   // seq
#define CD 512    // model dim

typedef float f32x4 __attribute__((ext_vector_type(4)));
typedef __bf16 bf16x8 __attribute__((ext_vector_type(8)));
typedef unsigned short u16;

#define MFMA(a, b, c) __builtin_amdgcn_mfma_f32_16x16x32_bf16((a), (b), (c), 0, 0, 0)
#define GLOAD16(g, l)                                                              \
  __builtin_amdgcn_global_load_lds((const __attribute__((address_space(1))) void*)(g), \
                                   (__attribute__((address_space(3))) void*)(l), 16, 0, 0)

__device__ __forceinline__ u16 f2bf(float f) {
  union { float f; unsigned u; } c; c.f = f;
  return (u16)((c.u + 0x7FFFu + ((c.u >> 16) & 1u)) >> 16);
}
__device__ __forceinline__ float bf2f(u16 h) {
  union { unsigned u; float f; } c; c.u = ((unsigned)h) << 16;
  return c.f;
}

// ---------------------------------------------------------------------------
// K0: LayerNorm for q,k,v -> xln bf16 [3*4096][512]; tail blocks convert W
// grid 13312 = 12288 LN + 1024 conv
// ---------------------------------------------------------------------------
__global__ __launch_bounds__(256) void ln_convw_kernel(const float* __restrict__ q,
                                                       const float* __restrict__ k,
                                                       const float* __restrict__ v,
                                                       const float* __restrict__ g,
                                                       const float* __restrict__ bb,
                                                       u16* __restrict__ xln,
                                                       const float* __restrict__ wi_f,
                                                       const float* __restrict__ wo_f,
                                                       u16* __restrict__ wi,
                                                       u16* __restrict__ wo) {
  int row = blockIdx.x;
  int tid = threadIdx.x;
  if (row >= 12288) {
    int i = (row - 12288) * 256 + tid;   // < 262144
    wi[i] = f2bf(wi_f[i]);
    wo[i] = f2bf(wo_f[i]);
    return;
  }
  int t = row >> 12;
  int rr = row & 4095;
  const float* src = (t == 0 ? q : (t == 1 ? k : v)) + (size_t)rr * CD;
  float x0 = src[tid], x1 = src[tid + 256];
  float s = x0 + x1, s2 = x0 * x0 + x1 * x1;
#pragma unroll
  for (int m = 1; m < 64; m <<= 1) { s += __shfl_xor(s, m); s2 += __shfl_xor(s2, m); }
  __shared__ float red[8];
  int w = tid >> 6;
  if ((tid & 63) == 0) { red[w] = s; red[4 + w] = s2; }
  __syncthreads();
  s = red[0] + red[1] + red[2] + red[3];
  s2 = red[4] + red[5] + red[6] + red[7];
  float mean = s * (1.f / 512.f);
  float var = s2 * (1.f / 512.f) - mean * mean;
  float rstd = rsqrtf(var + 1e-5f);
  u16* dst = xln + (size_t)row * CD;
  dst[tid]       = f2bf((x0 - mean) * rstd * g[tid] + bb[tid]);
  dst[tid + 256] = f2bf((x1 - mean) * rstd * g[tid + 256] + bb[tid + 256]);
}

// ---------------------------------------------------------------------------
// K1: gemm1 = xln @ Wi^T, BM=BN=128, BK=64, dbuf.
// tblk<32 (q rows): write F0cat[row][1024] = [iqn-scaled | plain] + qgp.
// tblk 32..63 (k): transpose to fkT + ikn + kgp; no C write.
// tblk 64..95 (v): transpose to fvT; no C write.
// ---------------------------------------------------------------------------
__global__ __launch_bounds__(256) void gemm1(const u16* __restrict__ A,
                                             const u16* __restrict__ Bt,
                                             u16* __restrict__ F0cat,
                                             float* __restrict__ ikn,
                                             float* __restrict__ qgp,
                                             float* __restrict__ kgp,
                                             u16* __restrict__ fkT,
                                             u16* __restrict__ fvT) {
  __shared__ u16 S[4][8192];
#define AL_(s) (S[s])
#define BL_(s) (S[2 + (s)])
  int tm = blockIdx.x * 128, tn = blockIdx.y * 128;
  int tid = threadIdx.x;
  int w = tid >> 6, l = tid & 63;
  int wr = w >> 1, wc = w & 1;
  int lo = l & 15, hi = l >> 4;

  f32x4 zz = {0.f, 0.f, 0.f, 0.f};
  f32x4 acc[4][4];
#pragma unroll
  for (int mi = 0; mi < 4; mi++)
#pragma unroll
    for (int ni = 0; ni < 4; ni++) acc[mi][ni] = zz;

  int rowA = 8 * w + (l >> 3);
  int sl = l & 7;

#pragma unroll
  for (int i = 0; i < 4; i++) {
    int rl = rowA + 32 * i;
    int sp = sl ^ (rl & 7);
    GLOAD16(A + (size_t)(tm + rl) * CD + sp * 8, (char*)AL_(0) + w * 1024 + i * 4096);
    GLOAD16(Bt + (size_t)(tn + rl) * CD + sp * 8, (char*)BL_(0) + w * 1024 + i * 4096);
  }
  __syncthreads();

  int cur = 0;
  for (int kt = 0; kt < 8; ++kt) {
    if (kt + 1 < 8) {
      int nxt = cur ^ 1;
#pragma unroll
      for (int i = 0; i < 4; i++) {
        int rl = rowA + 32 * i;
        int sp = sl ^ (rl & 7);
        GLOAD16(A + (size_t)(tm + rl) * CD + (kt + 1) * 64 + sp * 8,
                (char*)AL_(nxt) + w * 1024 + i * 4096);
        GLOAD16(Bt + (size_t)(tn + rl) * CD + (kt + 1) * 64 + sp * 8,
                (char*)BL_(nxt) + w * 1024 + i * 4096);
      }
    }
    const u16* Ac = AL_(cur);
    const u16* Bc = BL_(cur);
#pragma unroll
    for (int kk = 0; kk < 2; kk++) {
      bf16x8 af[4], bfr[4];
#pragma unroll
      for (int mi = 0; mi < 4; mi++) {
        int row = wr * 64 + mi * 16 + lo;
        int slot = (hi + 4 * kk) ^ (row & 7);
        af[mi] = *(const bf16x8*)&Ac[row * 64 + slot * 8];
      }
#pragma unroll
      for (int ni = 0; ni < 4; ni++) {
        int row = wc * 64 + ni * 16 + lo;
        int slot = (hi + 4 * kk) ^ (row & 7);
        bfr[ni] = *(const bf16x8*)&Bc[row * 64 + slot * 8];
      }
#pragma unroll
      for (int mi = 0; mi < 4; mi++)
#pragma unroll
        for (int ni = 0; ni < 4; ni++)
          acc[mi][ni] = MFMA(af[mi], bfr[ni], acc[mi][ni]);
    }
    if (kt + 1 < 8) {
      __syncthreads();
      cur ^= 1;
    }
  }

  int tblk = blockIdx.x;
  int h = blockIdx.y * 2 + wc;
  if (tblk < 32) {
    // ---- q rows: per-row inv-norm (all lanes) + qgp + F0cat dual write ----
    float rsq[4][4];
#pragma unroll
    for (int mi = 0; mi < 4; mi++)
#pragma unroll
      for (int rg = 0; rg < 4; rg++) {
        float s2 = 0.f;
#pragma unroll
        for (int ni = 0; ni < 4; ni++) {
          float vv = acc[mi][ni][rg];
          s2 += vv * vv;
        }
#pragma unroll
        for (int m = 1; m < 16; m <<= 1) s2 += __shfl_xor(s2, m);
        rsq[mi][rg] = rsqrtf(s2);
      }
    float cs[4];
#pragma unroll
    for (int ni = 0; ni < 4; ni++) {
      float s = 0.f;
#pragma unroll
      for (int mi = 0; mi < 4; mi++)
#pragma unroll
        for (int rg = 0; rg < 4; rg++) s += acc[mi][ni][rg];
      s += __shfl_xor(s, 16);
      s += __shfl_xor(s, 32);
      cs[ni] = s;
    }
    __syncthreads();
    float* redl = (float*)&S[0][0];
    if (hi == 0)
#pragma unroll
      for (int ni = 0; ni < 4; ni++) redl[((wr * 2 + wc) * 4 + ni) * 16 + lo] = cs[ni];
    __syncthreads();
    if (wr == 0 && hi == 0) {
#pragma unroll
      for (int ni = 0; ni < 4; ni++) {
        float vsum = redl[((0 * 2 + wc) * 4 + ni) * 16 + lo] +
                     redl[((1 * 2 + wc) * 4 + ni) * 16 + lo];
        qgp[(tblk * 8 + h) * 64 + ni * 16 + lo] = vsum;
      }
    }
#pragma unroll
    for (int mi = 0; mi < 4; mi++)
#pragma unroll
      for (int ni = 0; ni < 4; ni++) {
        int gcol = tn + wc * 64 + ni * 16 + lo;
#pragma unroll
        for (int rg = 0; rg < 4; rg++) {
          int rowg = tm + wr * 64 + mi * 16 + hi * 4 + rg;
          float vv = acc[mi][ni][rg];
          F0cat[(size_t)rowg * 1024 + gcol] = f2bf(rsq[mi][rg] * vv);
          F0cat[(size_t)rowg * 1024 + 512 + gcol] = f2bf(vv);
        }
      }
  } else {
    // ---- k/v rows: transpose to fkT/fvT; k also ikn + kgp ----
    bool isk = tblk < 64;
    u16* dstT = isk ? fkT : fvT;
    int rloc0 = tm - (isk ? 4096 : 8192);
    int bb2 = rloc0 >> 11, n0 = rloc0 & 2047;
    float csk[4];
    if (isk) {
#pragma unroll
      for (int mi = 0; mi < 4; mi++)
#pragma unroll
        for (int rg = 0; rg < 4; rg++) {
          float s2 = 0.f;
#pragma unroll
          for (int ni = 0; ni < 4; ni++) {
            float vv = acc[mi][ni][rg];
            s2 += vv * vv;
          }
#pragma unroll
          for (int m = 1; m < 16; m <<= 1) s2 += __shfl_xor(s2, m);
          if (lo == 0) {
            int n = n0 + wr * 64 + mi * 16 + hi * 4 + rg;
            ikn[((size_t)h * 2 + bb2) * CN + n] = rsqrtf(s2);
          }
        }
#pragma unroll
      for (int ni = 0; ni < 4; ni++) {
        float s = 0.f;
#pragma unroll
        for (int mi = 0; mi < 4; mi++)
#pragma unroll
          for (int rg = 0; rg < 4; rg++) s += acc[mi][ni][rg];
        s += __shfl_xor(s, 16);
        s += __shfl_xor(s, 32);
        csk[ni] = s;
      }
    }
    __syncthreads();
    u16* Sf = &S[0][0];
    int reg = wc * 2 + wr;
#pragma unroll
    for (int mi = 0; mi < 4; mi++)
#pragma unroll
      for (int ni = 0; ni < 4; ni++) {
        int d = ni * 16 + lo;
        int m0 = mi * 16 + hi * 4;
        u16 t4[4];
#pragma unroll
        for (int rg = 0; rg < 4; rg++) t4[rg] = f2bf(acc[mi][ni][rg]);
        int off = (reg * 64 + d) * 64 + (m0 ^ ((d & 7) << 3));
        *(uint2*)&Sf[off] = *(const uint2*)t4;
      }
    __syncthreads();
    {
      int head = tid >> 7, c = tid & 127;
      int hg = blockIdx.y * 2 + head;
      size_t base = ((size_t)(hg * 2 + bb2)) * 64 * CN;
#pragma unroll
      for (int p = 0; p < 8; p++) {
        int flat = p * 128 + c;
        int d = flat >> 4, mc = flat & 15;
        int wr2 = mc >> 3, m64 = (mc & 7) * 8;
        int off = ((head * 2 + wr2) * 64 + d) * 64 + (m64 ^ ((d & 7) << 3));
        bf16x8 vv = *(const bf16x8*)&Sf[off];
        *(bf16x8*)&dstT[base + (size_t)d * CN + n0 + mc * 8] = vv;
      }
    }
    if (isk) {
      __syncthreads();
      float* redl = (float*)&S[0][0];
      if (hi == 0)
#pragma unroll
        for (int ni = 0; ni < 4; ni++) redl[((wr * 2 + wc) * 4 + ni) * 16 + lo] = csk[ni];
      __syncthreads();
      if (wr == 0 && hi == 0) {
#pragma unroll
        for (int ni = 0; ni < 4; ni++) {
          float vsum = redl[((0 * 2 + wc) * 4 + ni) * 16 + lo] +
                       redl[((1 * 2 + wc) * 4 + ni) * 16 + lo];
          kgp[((tblk - 32) * 8 + h) * 64 + ni * 16 + lo] = vsum;
        }
      }
    }
  }
#undef AL_
#undef BL_
}

// ---------------------------------------------------------------------------
// K3: gemm_M_mlp_w — grid 16 (hb), 256 thr. Per hb:
//  ph0: MLP (wave 0) -> alpha/beta/gamma
//  ph1: M1 = (K*ikn)^T V, M2 = K^T V (full K=2048, dbuf staging, T14 reg-scale)
//  ph2: S2[d] = colsum(M2); ph3: M1b = a*M1, Cb = b*M2 - (g/4096)*S2 (bf16 LDS)
//  ph4: Wbig[b][dout][h*64+i] = Wo_h @ M1b^T ; [.. 512+..] = Wo_h @ Cb^T
// ---------------------------------------------------------------------------
__global__ __launch_bounds__(256) void gemm_M_mlp_w(
    const u16* __restrict__ fkT, const u16* __restrict__ fvT,
    const float* __restrict__ ikn, const float* __restrict__ qgp,
    const float* __restrict__ kgp, const float* __restrict__ w1,
    const float* __restrict__ b1, const float* __restrict__ lng,
    const float* __restrict__ lnb, const float* __restrict__ w2,
    const float* __restrict__ b2, const u16* __restrict__ Wo,
    u16* __restrict__ Wbig) {
  int hb = blockIdx.x;
  int h = hb >> 1, b = hb & 1;
  int tid = threadIdx.x, w = tid >> 6, l = tid & 63;
  int lo = l & 15, hi = l >> 4;

  __shared__ u16 GM[6][4096];     // staging: Ak[2], Akh[2], Bv[2] (48 KB)
#define AK_(s) (GM[s])
#define AKH_(s) (GM[2 + (s)])
#define BV_(s) (GM[4 + (s)])
  __shared__ float abg[3];
  __shared__ float Msf[64][65];   // M2 f32 / MLP scratch
  __shared__ float S2s[64];
  __shared__ u16 M1b[64 * 72];
  __shared__ u16 Cb[64 * 72];

  // phase 0: MLP on wave 0 (same-wave LDS ordering; abg consumed after barriers)
  if (tid < 64) {
    float s1 = 0.f, s2 = 0.f;
#pragma unroll
    for (int c = 0; c < 32; c++) {
      s1 += qgp[(c * 8 + h) * 64 + tid];
      s2 += kgp[(c * 8 + h) * 64 + tid];
    }
    Msf[0][tid] = s1 * (1.f / 4096.f);
    Msf[1][tid] = s2 * (1.f / 4096.f);
    float acc = b1[tid];
#pragma unroll 8
    for (int i = 0; i < 64; i++)
      acc += Msf[0][i] * w1[tid * 128 + i] + Msf[1][i] * w1[tid * 128 + 64 + i];
    float t1 = acc, t2 = acc * acc;
#pragma unroll
    for (int m = 1; m < 64; m <<= 1) { t1 += __shfl_xor(t1, m); t2 += __shfl_xor(t2, m); }
    float mean = t1 * (1.f / 64.f);
    float var = t2 * (1.f / 64.f) - mean * mean;
    float y = (acc - mean) * rsqrtf(var + 1e-5f) * lng[tid] + lnb[tid];
    float hid = fmaxf(y, 0.f);
    float t = hid * w2[tid];
#pragma unroll
    for (int m = 1; m < 64; m <<= 1) t += __shfl_xor(t, m);
    float wv = 1.f / (1.f + expf(-(t + b2[0])));
    if (tid == 0) { abg[0] = 1.f - wv; abg[1] = wv * (1.f / 64.f); abg[2] = wv; }
  }

  // phase 1: gemm_M full-K
  const u16* Ab = fkT + (size_t)hb * 64 * CN;
  const u16* Vb = fvT + (size_t)hb * 64 * CN;
  const float* ikb = ikn + (size_t)hb * CN;

  f32x4 zz = {0.f, 0.f, 0.f, 0.f};
  f32x4 acc[2][4];
#pragma unroll
  for (int mat = 0; mat < 2; mat++)
#pragma unroll
    for (int dt = 0; dt < 4; dt++) acc[mat][dt] = zz;

  int rls = 8 * w + (l >> 3);
  int sls = l & 7;
  bf16x8 areg[2];
  f32x4 ikreg[2][2];

  auto STAGEGL = [&](int kt, int slot) {
    int mc = kt * 64;
#pragma unroll
    for (int i = 0; i < 2; i++) {
      int row = rls + 32 * i;
      int sp = sls ^ (row & 7);
      GLOAD16(Ab + (size_t)row * CN + mc + sp * 8, (char*)AK_(slot) + w * 1024 + i * 4096);
      GLOAD16(Vb + (size_t)row * CN + mc + sp * 8, (char*)BV_(slot) + w * 1024 + i * 4096);
    }
  };
  auto LOADA = [&](int kt) {
    int mc = kt * 64;
#pragma unroll
    for (int i = 0; i < 2; i++) {
      int row = rls + 32 * i;
      int sp = sls ^ (row & 7);
      areg[i] = *(const bf16x8*)&Ab[(size_t)row * CN + mc + sp * 8];
      ikreg[i][0] = *(const f32x4*)&ikb[mc + sp * 8];
      ikreg[i][1] = *(const f32x4*)&ikb[mc + sp * 8 + 4];
    }
  };
  auto WRITEA = [&](int slot) {
#pragma unroll
    for (int i = 0; i < 2; i++) {
      u16 outp[8];
#pragma unroll
      for (int j = 0; j < 4; j++) outp[j] = f2bf((float)areg[i][j] * ikreg[i][0][j]);
#pragma unroll
      for (int j = 0; j < 4; j++) outp[4 + j] = f2bf((float)areg[i][4 + j] * ikreg[i][1][j]);
      *(bf16x8*)((char*)AKH_(slot) + w * 1024 + i * 4096 + l * 16) = *(const bf16x8*)outp;
    }
  };

  LOADA(0);
  STAGEGL(0, 0);
  WRITEA(0);
  __syncthreads();

  int cur = 0;
  for (int kt = 0; kt < 32; ++kt) {
    if (kt + 1 < 32) {
      LOADA(kt + 1);
      STAGEGL(kt + 1, cur ^ 1);
    }
#pragma unroll
    for (int kk = 0; kk < 2; kk++) {
      int arow = w * 16 + lo;
      int aslot = (hi + 4 * kk) ^ (arow & 7);
      bf16x8 af = *(const bf16x8*)&AK_(cur)[arow * 64 + aslot * 8];
      bf16x8 afh = *(const bf16x8*)&AKH_(cur)[arow * 64 + aslot * 8];
#pragma unroll
      for (int dt = 0; dt < 4; dt++) {
        int brow = dt * 16 + lo;
        int bslot = (hi + 4 * kk) ^ (brow & 7);
        bf16x8 bv = *(const bf16x8*)&BV_(cur)[brow * 64 + bslot * 8];
        acc[0][dt] = MFMA(afh, bv, acc[0][dt]);   // M1 (ikn-scaled K)
        acc[1][dt] = MFMA(af, bv, acc[1][dt]);    // M2
      }
    }
    if (kt + 1 < 32) {
      WRITEA(cur ^ 1);
      __syncthreads();
      cur ^= 1;
    }
  }

  // phase 2: M2 -> LDS f32, colsum S2
  __syncthreads();
#pragma unroll
  for (int dt = 0; dt < 4; dt++)
#pragma unroll
    for (int rg = 0; rg < 4; rg++)
      Msf[w * 16 + hi * 4 + rg][dt * 16 + lo] = acc[1][dt][rg];
  __syncthreads();
  if (tid < 64) {
    float s = 0.f;
#pragma unroll
    for (int i = 0; i < 64; i++) s += Msf[i][tid];
    S2s[tid] = s;
  }
  __syncthreads();

  // phase 3: bf16 B-operands
  float alpha = abg[0], beta = abg[1], g4 = abg[2] * (1.f / 4096.f);
#pragma unroll
  for (int dt = 0; dt < 4; dt++)
#pragma unroll
    for (int rg = 0; rg < 4; rg++) {
      int i = w * 16 + hi * 4 + rg, d = dt * 16 + lo;
      M1b[i * 72 + d] = f2bf(alpha * acc[0][dt][rg]);
      Cb[i * 72 + d] = f2bf(beta * acc[1][dt][rg] - g4 * S2s[d]);
    }
  __syncthreads();

  // phase 4: Wbig build — wave w: dout rows [w*128, w*128+128)
  u16* Wb = Wbig + (size_t)b * 512 * 1024;
#pragma unroll
  for (int rf = 0; rf < 8; rf++) {
    int dbase = w * 128 + rf * 16;
    bf16x8 af[2];
#pragma unroll
    for (int kk = 0; kk < 2; kk++)
      af[kk] = *(const bf16x8*)&Wo[(size_t)(dbase + lo) * 512 + h * 64 + kk * 32 + hi * 8];
    f32x4 a1[4], a2[4];
#pragma unroll
    for (int cf = 0; cf < 4; cf++) { a1[cf] = zz; a2[cf] = zz; }
#pragma unroll
    for (int kk = 0; kk < 2; kk++)
#pragma unroll
      for (int cf = 0; cf < 4; cf++) {
        bf16x8 m1 = *(const bf16x8*)&M1b[(cf * 16 + lo) * 72 + kk * 32 + hi * 8];
        bf16x8 cb = *(const bf16x8*)&Cb[(cf * 16 + lo) * 72 + kk * 32 + hi * 8];
        a1[cf] = MFMA(af[kk], m1, a1[cf]);
        a2[cf] = MFMA(af[kk], cb, a2[cf]);
      }
#pragma unroll
    for (int cf = 0; cf < 4; cf++)
#pragma unroll
      for (int rg = 0; rg < 4; rg++) {
        int dout = dbase + hi * 4 + rg;
        int icol = cf * 16 + lo;
        Wb[(size_t)dout * 1024 + h * 64 + icol] = f2bf(a1[cf][rg]);
        Wb[(size_t)dout * 1024 + 512 + h * 64 + icol] = f2bf(a2[cf][rg]);
      }
  }
#undef AK_
#undef AKH_
#undef BV_
}

// ---------------------------------------------------------------------------
// K4: gemm_final — out = F0cat @ Wbig[b]^T + b_out (f32). K=1024, BK=64, dbuf.
// grid (32,4); b = blockIdx.x>=16.
// ---------------------------------------------------------------------------
__global__ __launch_bounds__(256) void gemm_final(const u16* __restrict__ A,
                                                  const u16* __restrict__ Wbig,
                                                  const float* __restrict__ bias,
                                                  float* __restrict__ Cout) {
  __shared__ u16 Al[2][128 * 64];
  __shared__ u16 Bl[2][128 * 64];
  int tm = blockIdx.x * 128, tn = blockIdx.y * 128;
  const u16* Bt = Wbig + (size_t)(tm >> 11) * 512 * 1024;
  int tid = threadIdx.x;
  int w = tid >> 6, l = tid & 63;
  int wr = w >> 1, wc = w & 1;
  int lo = l & 15, hi = l >> 4;

  f32x4 zz = {0.f, 0.f, 0.f, 0.f};
  f32x4 acc[4][4];
#pragma unroll
  for (int mi = 0; mi < 4; mi++)
#pragma unroll
    for (int ni = 0; ni < 4; ni++) acc[mi][ni] = zz;

  int rowA = 8 * w + (l >> 3);
  int sl = l & 7;

#pragma unroll
  for (int i = 0; i < 4; i++) {
    int rl = rowA + 32 * i;
    int sp = sl ^ (rl & 7);
    GLOAD16(A + (size_t)(tm + rl) * 1024 + sp * 8, (char*)Al[0] + w * 1024 + i * 4096);
    GLOAD16(Bt + (size_t)(tn + rl) * 1024 + sp * 8, (char*)Bl[0] + w * 1024 + i * 4096);
  }
  __syncthreads();

  int cur = 0;
  for (int kt = 0; kt < 16; ++kt) {
    if (kt + 1 < 16) {
      int nxt = cur ^ 1;
#pragma unroll
      for (int i = 0; i < 4; i++) {
        int rl = rowA + 32 * i;
        int sp = sl ^ (rl & 7);
        GLOAD16(A + (size_t)(tm + rl) * 1024 + (kt + 1) * 64 + sp * 8,
                (char*)Al[nxt] + w * 1024 + i * 4096);
        GLOAD16(Bt + (size_t)(tn + rl) * 1024 + (kt + 1) * 64 + sp * 8,
                (char*)Bl[nxt] + w * 1024 + i * 4096);
      }
    }
    const u16* Ac = Al[cur];
    const u16* Bc = Bl[cur];
#pragma unroll
    for (int kk = 0; kk < 2; kk++) {
      bf16x8 af[4], bfr[4];
#pragma unroll
      for (int mi = 0; mi < 4; mi++) {
        int row = wr * 64 + mi * 16 + lo;
        int slot = (hi + 4 * kk) ^ (row & 7);
        af[mi] = *(const bf16x8*)&Ac[row * 64 + slot * 8];
      }
#pragma unroll
      for (int ni = 0; ni < 4; ni++) {
        int row = wc * 64 + ni * 16 + lo;
        int slot = (hi + 4 * kk) ^ (row & 7);
        bfr[ni] = *(const bf16x8*)&Bc[row * 64 + slot * 8];
      }
#pragma unroll
      for (int mi = 0; mi < 4; mi++)
#pragma unroll
        for (int ni = 0; ni < 4; ni++)
          acc[mi][ni] = MFMA(af[mi], bfr[ni], acc[mi][ni]);
    }
    if (kt + 1 < 16) {
      __syncthreads();
      cur ^= 1;
    }
  }
#pragma unroll
  for (int mi = 0; mi < 4; mi++)
#pragma unroll
    for (int ni = 0; ni < 4; ni++) {
      int col = tn + wc * 64 + ni * 16 + lo;
      float bv = bias[col];
#pragma unroll
      for (int rg = 0; rg < 4; rg++) {
        int rowg = tm + wr * 64 + mi * 16 + hi * 4 + rg;
        Cout[(size_t)rowg * CD + col] = acc[mi][ni][rg] + bv;
      }
    }
}

// ---------------------------------------------------------------------------
extern "C" void kernel_launch(void* const* d_in, const int* in_sizes, int n_in,
                              void* d_out, int out_size, void* d_ws, size_t ws_size,
                              hipStream_t stream) {
  const float* q = (const float*)d_in[0];
  const float* k = (const float*)d_in[1];
  const float* v = (const float*)d_in[2];
  const float* ln_g = (const float*)d_in[3];
  const float* ln_b = (const float*)d_in[4];
  const float* W_in = (const float*)d_in[5];
  const float* wp_w1 = (const float*)d_in[6];
  const float* wp_b1 = (const float*)d_in[7];
  const float* wp_lng = (const float*)d_in[8];
  const float* wp_lnb = (const float*)d_in[9];
  const float* wp_w2 = (const float*)d_in[10];
  const float* wp_b2 = (const float*)d_in[11];
  const float* W_out = (const float*)d_in[12];
  const float* b_out = (const float*)d_in[13];

  char* ws = (char*)d_ws;
  u16* xln = (u16*)(ws + 0);              // 12,582,912 B  [3*4096][512]
  u16* F0cat = (u16*)(ws + 12582912);     // 8,388,608 B   [4096][1024]
  u16* Wi = (u16*)(ws + 20971520);        // 524,288 B
  u16* Wo = (u16*)(ws + 21495808);        // 524,288 B
  u16* fkT = (u16*)(ws + 22020096);       // 4,194,304 B   [HB][64][2048]
  u16* fvT = (u16*)(ws + 26214400);       // 4,194,304 B
  float* ikn = (float*)(ws + 30408704);   // 131,072 B
  float* qgp = (float*)(ws + 30539776);   // 65,536 B
  float* kgp = (float*)(ws + 30605312);   // 65,536 B
  u16* Wbig = (u16*)(ws + 30670848);      // 2,097,152 B   [2][512][1024] bf16

  ln_convw_kernel<<<13312, 256, 0, stream>>>(q, k, v, ln_g, ln_b, xln,
                                             W_in, W_out, Wi, Wo);
  gemm1<<<dim3(96, 4), 256, 0, stream>>>(xln, Wi, F0cat, ikn, qgp, kgp, fkT, fvT);
  gemm_M_mlp_w<<<16, 256, 0, stream>>>(fkT, fvT, ikn, qgp, kgp, wp_w1, wp_b1,
                                       wp_lng, wp_lnb, wp_w2, wp_b2, Wo, Wbig);
  gemm_final<<<dim3(32, 4), 256, 0, stream>>>(F0cat, Wbig, b_out, (float*)d_out);
}

// Round 13
// 74.613 us; speedup vs baseline: 1.3188x; 1.3188x over previous
//
#include <hip/hip_runtime.h>
#include <stdint.h>

// Problem constants
#define CH 8      // heads
#define CDH 64    // dim head
#define CB 2      // batch
#define CN 2048   // seq
#define CD 512    // model dim

typedef float f32x4 __attribute__((ext_vector_type(4)));
typedef __bf16 bf16x8 __attribute__((ext_vector_type(8)));
typedef unsigned short u16;

#define MFMA(a, b, c) __builtin_amdgcn_mfma_f32_16x16x32_bf16((a), (b), (c), 0, 0, 0)
#define GLOAD16(g, l)                                                              \
  __builtin_amdgcn_global_load_lds((const __attribute__((address_space(1))) void*)(g), \
                                   (__attribute__((address_space(3))) void*)(l), 16, 0, 0)

__device__ __forceinline__ u16 f2bf(float f) {
  union { float f; unsigned u; } c; c.f = f;
  return (u16)((c.u + 0x7FFFu + ((c.u >> 16) & 1u)) >> 16);
}
__device__ __forceinline__ float bf2f(u16 h) {
  union { unsigned u; float f; } c; c.u = ((unsigned)h) << 16;
  return c.f;
}

// ---------------------------------------------------------------------------
// K0: LayerNorm for q,k,v -> xln bf16 [3*4096][512]; tail blocks convert W
// grid 13312 = 12288 LN + 1024 conv
// ---------------------------------------------------------------------------
__global__ __launch_bounds__(256) void ln_convw_kernel(const float* __restrict__ q,
                                                       const float* __restrict__ k,
                                                       const float* __restrict__ v,
                                                       const float* __restrict__ g,
                                                       const float* __restrict__ bb,
                                                       u16* __restrict__ xln,
                                                       const float* __restrict__ wi_f,
                                                       const float* __restrict__ wo_f,
                                                       u16* __restrict__ wi,
                                                       u16* __restrict__ wo) {
  int row = blockIdx.x;
  int tid = threadIdx.x;
  if (row >= 12288) {
    int i = (row - 12288) * 256 + tid;   // < 262144
    wi[i] = f2bf(wi_f[i]);
    wo[i] = f2bf(wo_f[i]);
    return;
  }
  int t = row >> 12;
  int rr = row & 4095;
  const float* src = (t == 0 ? q : (t == 1 ? k : v)) + (size_t)rr * CD;
  float x0 = src[tid], x1 = src[tid + 256];
  float s = x0 + x1, s2 = x0 * x0 + x1 * x1;
#pragma unroll
  for (int m = 1; m < 64; m <<= 1) { s += __shfl_xor(s, m); s2 += __shfl_xor(s2, m); }
  __shared__ float red[8];
  int w = tid >> 6;
  if ((tid & 63) == 0) { red[w] = s; red[4 + w] = s2; }
  __syncthreads();
  s = red[0] + red[1] + red[2] + red[3];
  s2 = red[4] + red[5] + red[6] + red[7];
  float mean = s * (1.f / 512.f);
  float var = s2 * (1.f / 512.f) - mean * mean;
  float rstd = rsqrtf(var + 1e-5f);
  u16* dst = xln + (size_t)row * CD;
  dst[tid]       = f2bf((x0 - mean) * rstd * g[tid] + bb[tid]);
  dst[tid + 256] = f2bf((x1 - mean) * rstd * g[tid + 256] + bb[tid + 256]);
}

// ---------------------------------------------------------------------------
// K1: gemm1 = xln @ Wi^T, BM=BN=128, BK=64, dbuf.
// tblk<32 (q rows): write F0cat[row][1024] = [iqn-scaled | plain] + qgp.
// tblk 32..63 (k): transpose to fkT + ikn + kgp; no C write.
// tblk 64..95 (v): transpose to fvT; no C write.
// ---------------------------------------------------------------------------
__global__ __launch_bounds__(256) void gemm1(const u16* __restrict__ A,
                                             const u16* __restrict__ Bt,
                                             u16* __restrict__ F0cat,
                                             float* __restrict__ ikn,
                                             float* __restrict__ qgp,
                                             float* __restrict__ kgp,
                                             u16* __restrict__ fkT,
                                             u16* __restrict__ fvT) {
  __shared__ u16 S[4][8192];
#define AL_(s) (S[s])
#define BL_(s) (S[2 + (s)])
  int tm = blockIdx.x * 128, tn = blockIdx.y * 128;
  int tid = threadIdx.x;
  int w = tid >> 6, l = tid & 63;
  int wr = w >> 1, wc = w & 1;
  int lo = l & 15, hi = l >> 4;

  f32x4 zz = {0.f, 0.f, 0.f, 0.f};
  f32x4 acc[4][4];
#pragma unroll
  for (int mi = 0; mi < 4; mi++)
#pragma unroll
    for (int ni = 0; ni < 4; ni++) acc[mi][ni] = zz;

  int rowA = 8 * w + (l >> 3);
  int sl = l & 7;

#pragma unroll
  for (int i = 0; i < 4; i++) {
    int rl = rowA + 32 * i;
    int sp = sl ^ (rl & 7);
    GLOAD16(A + (size_t)(tm + rl) * CD + sp * 8, (char*)AL_(0) + w * 1024 + i * 4096);
    GLOAD16(Bt + (size_t)(tn + rl) * CD + sp * 8, (char*)BL_(0) + w * 1024 + i * 4096);
  }
  __syncthreads();

  int cur = 0;
  for (int kt = 0; kt < 8; ++kt) {
    if (kt + 1 < 8) {
      int nxt = cur ^ 1;
#pragma unroll
      for (int i = 0; i < 4; i++) {
        int rl = rowA + 32 * i;
        int sp = sl ^ (rl & 7);
        GLOAD16(A + (size_t)(tm + rl) * CD + (kt + 1) * 64 + sp * 8,
                (char*)AL_(nxt) + w * 1024 + i * 4096);
        GLOAD16(Bt + (size_t)(tn + rl) * CD + (kt + 1) * 64 + sp * 8,
                (char*)BL_(nxt) + w * 1024 + i * 4096);
      }
    }
    const u16* Ac = AL_(cur);
    const u16* Bc = BL_(cur);
#pragma unroll
    for (int kk = 0; kk < 2; kk++) {
      bf16x8 af[4], bfr[4];
#pragma unroll
      for (int mi = 0; mi < 4; mi++) {
        int row = wr * 64 + mi * 16 + lo;
        int slot = (hi + 4 * kk) ^ (row & 7);
        af[mi] = *(const bf16x8*)&Ac[row * 64 + slot * 8];
      }
#pragma unroll
      for (int ni = 0; ni < 4; ni++) {
        int row = wc * 64 + ni * 16 + lo;
        int slot = (hi + 4 * kk) ^ (row & 7);
        bfr[ni] = *(const bf16x8*)&Bc[row * 64 + slot * 8];
      }
#pragma unroll
      for (int mi = 0; mi < 4; mi++)
#pragma unroll
        for (int ni = 0; ni < 4; ni++)
          acc[mi][ni] = MFMA(af[mi], bfr[ni], acc[mi][ni]);
    }
    if (kt + 1 < 8) {
      __syncthreads();
      cur ^= 1;
    }
  }

  int tblk = blockIdx.x;
  int h = blockIdx.y * 2 + wc;
  if (tblk < 32) {
    // ---- q rows: per-row inv-norm (all lanes) + qgp + F0cat dual write ----
    float rsq[4][4];
#pragma unroll
    for (int mi = 0; mi < 4; mi++)
#pragma unroll
      for (int rg = 0; rg < 4; rg++) {
        float s2 = 0.f;
#pragma unroll
        for (int ni = 0; ni < 4; ni++) {
          float vv = acc[mi][ni][rg];
          s2 += vv * vv;
        }
#pragma unroll
        for (int m = 1; m < 16; m <<= 1) s2 += __shfl_xor(s2, m);
        rsq[mi][rg] = rsqrtf(s2);
      }
    float cs[4];
#pragma unroll
    for (int ni = 0; ni < 4; ni++) {
      float s = 0.f;
#pragma unroll
      for (int mi = 0; mi < 4; mi++)
#pragma unroll
        for (int rg = 0; rg < 4; rg++) s += acc[mi][ni][rg];
      s += __shfl_xor(s, 16);
      s += __shfl_xor(s, 32);
      cs[ni] = s;
    }
    __syncthreads();
    float* redl = (float*)&S[0][0];
    if (hi == 0)
#pragma unroll
      for (int ni = 0; ni < 4; ni++) redl[((wr * 2 + wc) * 4 + ni) * 16 + lo] = cs[ni];
    __syncthreads();
    if (wr == 0 && hi == 0) {
#pragma unroll
      for (int ni = 0; ni < 4; ni++) {
        float vsum = redl[((0 * 2 + wc) * 4 + ni) * 16 + lo] +
                     redl[((1 * 2 + wc) * 4 + ni) * 16 + lo];
        qgp[(tblk * 8 + h) * 64 + ni * 16 + lo] = vsum;
      }
    }
#pragma unroll
    for (int mi = 0; mi < 4; mi++)
#pragma unroll
      for (int ni = 0; ni < 4; ni++) {
        int gcol = tn + wc * 64 + ni * 16 + lo;
#pragma unroll
        for (int rg = 0; rg < 4; rg++) {
          int rowg = tm + wr * 64 + mi * 16 + hi * 4 + rg;
          float vv = acc[mi][ni][rg];
          F0cat[(size_t)rowg * 1024 + gcol] = f2bf(rsq[mi][rg] * vv);
          F0cat[(size_t)rowg * 1024 + 512 + gcol] = f2bf(vv);
        }
      }
  } else {
    // ---- k/v rows: transpose to fkT/fvT; k also ikn + kgp ----
    bool isk = tblk < 64;
    u16* dstT = isk ? fkT : fvT;
    int rloc0 = tm - (isk ? 4096 : 8192);
    int bb2 = rloc0 >> 11, n0 = rloc0 & 2047;
    float csk[4];
    if (isk) {
#pragma unroll
      for (int mi = 0; mi < 4; mi++)
#pragma unroll
        for (int rg = 0; rg < 4; rg++) {
          float s2 = 0.f;
#pragma unroll
          for (int ni = 0; ni < 4; ni++) {
            float vv = acc[mi][ni][rg];
            s2 += vv * vv;
          }
#pragma unroll
          for (int m = 1; m < 16; m <<= 1) s2 += __shfl_xor(s2, m);
          if (lo == 0) {
            int n = n0 + wr * 64 + mi * 16 + hi * 4 + rg;
            ikn[((size_t)h * 2 + bb2) * CN + n] = rsqrtf(s2);
          }
        }
#pragma unroll
      for (int ni = 0; ni < 4; ni++) {
        float s = 0.f;
#pragma unroll
        for (int mi = 0; mi < 4; mi++)
#pragma unroll
          for (int rg = 0; rg < 4; rg++) s += acc[mi][ni][rg];
        s += __shfl_xor(s, 16);
        s += __shfl_xor(s, 32);
        csk[ni] = s;
      }
    }
    __syncthreads();
    u16* Sf = &S[0][0];
    int reg = wc * 2 + wr;
#pragma unroll
    for (int mi = 0; mi < 4; mi++)
#pragma unroll
      for (int ni = 0; ni < 4; ni++) {
        int d = ni * 16 + lo;
        int m0 = mi * 16 + hi * 4;
        u16 t4[4];
#pragma unroll
        for (int rg = 0; rg < 4; rg++) t4[rg] = f2bf(acc[mi][ni][rg]);
        int off = (reg * 64 + d) * 64 + (m0 ^ ((d & 7) << 3));
        *(uint2*)&Sf[off] = *(const uint2*)t4;
      }
    __syncthreads();
    {
      int head = tid >> 7, c = tid & 127;
      int hg = blockIdx.y * 2 + head;
      size_t base = ((size_t)(hg * 2 + bb2)) * 64 * CN;
#pragma unroll
      for (int p = 0; p < 8; p++) {
        int flat = p * 128 + c;
        int d = flat >> 4, mc = flat & 15;
        int wr2 = mc >> 3, m64 = (mc & 7) * 8;
        int off = ((head * 2 + wr2) * 64 + d) * 64 + (m64 ^ ((d & 7) << 3));
        bf16x8 vv = *(const bf16x8*)&Sf[off];
        *(bf16x8*)&dstT[base + (size_t)d * CN + n0 + mc * 8] = vv;
      }
    }
    if (isk) {
      __syncthreads();
      float* redl = (float*)&S[0][0];
      if (hi == 0)
#pragma unroll
        for (int ni = 0; ni < 4; ni++) redl[((wr * 2 + wc) * 4 + ni) * 16 + lo] = csk[ni];
      __syncthreads();
      if (wr == 0 && hi == 0) {
#pragma unroll
        for (int ni = 0; ni < 4; ni++) {
          float vsum = redl[((0 * 2 + wc) * 4 + ni) * 16 + lo] +
                       redl[((1 * 2 + wc) * 4 + ni) * 16 + lo];
          kgp[((tblk - 32) * 8 + h) * 64 + ni * 16 + lo] = vsum;
        }
      }
    }
  }
#undef AL_
#undef BL_
}

// ---------------------------------------------------------------------------
// K2: gemm_M — per (h,b): M1 = (K*ikn)^T V, M2 = K^T V (64x64 each), m-split 4.
// grid 64 (hb:4 low | ms:2), 256 threads. Ak,Bv via global_load_lds; Akh
// reg-staged (load->scale by ikn[m]->ds_write) hidden under MFMA (T14).
// Mpart[(hb*4+ms)][j=mat*64+i][d] f32.   (R11-proven structure)
// ---------------------------------------------------------------------------
__global__ __launch_bounds__(256) void gemm_M(const u16* __restrict__ fkT,
                                              const u16* __restrict__ fvT,
                                              const float* __restrict__ ikn,
                                              float* __restrict__ Mpart) {
  int bid = blockIdx.x;
  int hb = bid & 15, ms = bid >> 4;   // ms in [0,4)
  int tid = threadIdx.x, w = tid >> 6, l = tid & 63;
  int lo = l & 15, hi = l >> 4;

  __shared__ u16 GM[6][4096];   // Ak[2], Akh[2], Bv[2]
#define AK_(s) (GM[s])
#define AKH_(s) (GM[2 + (s)])
#define BV_(s) (GM[4 + (s)])

  const u16* Ab = fkT + (size_t)hb * 64 * CN;
  const u16* Vb = fvT + (size_t)hb * 64 * CN;
  const float* ikb = ikn + (size_t)hb * CN;

  f32x4 zz = {0.f, 0.f, 0.f, 0.f};
  f32x4 acc[2][4];
#pragma unroll
  for (int mat = 0; mat < 2; mat++)
#pragma unroll
    for (int dt = 0; dt < 4; dt++) acc[mat][dt] = zz;

  int rls = 8 * w + (l >> 3);
  int sls = l & 7;

  bf16x8 areg[2];
  f32x4 ikreg[2][2];

  auto STAGEGL = [&](int kt, int slot) {
    int mc = ms * 512 + kt * 64;
#pragma unroll
    for (int i = 0; i < 2; i++) {
      int row = rls + 32 * i;
      int sp = sls ^ (row & 7);
      GLOAD16(Ab + (size_t)row * CN + mc + sp * 8, (char*)AK_(slot) + w * 1024 + i * 4096);
      GLOAD16(Vb + (size_t)row * CN + mc + sp * 8, (char*)BV_(slot) + w * 1024 + i * 4096);
    }
  };
  auto LOADA = [&](int kt) {
    int mc = ms * 512 + kt * 64;
#pragma unroll
    for (int i = 0; i < 2; i++) {
      int row = rls + 32 * i;
      int sp = sls ^ (row & 7);
      areg[i] = *(const bf16x8*)&Ab[(size_t)row * CN + mc + sp * 8];
      ikreg[i][0] = *(const f32x4*)&ikb[mc + sp * 8];
      ikreg[i][1] = *(const f32x4*)&ikb[mc + sp * 8 + 4];
    }
  };
  auto WRITEA = [&](int slot) {
#pragma unroll
    for (int i = 0; i < 2; i++) {
      u16 outp[8];
#pragma unroll
      for (int j = 0; j < 4; j++) outp[j] = f2bf((float)areg[i][j] * ikreg[i][0][j]);
#pragma unroll
      for (int j = 0; j < 4; j++) outp[4 + j] = f2bf((float)areg[i][4 + j] * ikreg[i][1][j]);
      *(bf16x8*)((char*)AKH_(slot) + w * 1024 + i * 4096 + l * 16) = *(const bf16x8*)outp;
    }
  };

  LOADA(0);
  STAGEGL(0, 0);
  WRITEA(0);
  __syncthreads();

  int cur = 0;
  for (int kt = 0; kt < 8; ++kt) {
    if (kt + 1 < 8) {
      LOADA(kt + 1);
      STAGEGL(kt + 1, cur ^ 1);
    }
#pragma unroll
    for (int kk = 0; kk < 2; kk++) {
      int arow = w * 16 + lo;
      int aslot = (hi + 4 * kk) ^ (arow & 7);
      bf16x8 af = *(const bf16x8*)&AK_(cur)[arow * 64 + aslot * 8];
      bf16x8 afh = *(const bf16x8*)&AKH_(cur)[arow * 64 + aslot * 8];
#pragma unroll
      for (int dt = 0; dt < 4; dt++) {
        int brow = dt * 16 + lo;
        int bslot = (hi + 4 * kk) ^ (brow & 7);
        bf16x8 bv = *(const bf16x8*)&BV_(cur)[brow * 64 + bslot * 8];
        acc[0][dt] = MFMA(afh, bv, acc[0][dt]);   // M1 (ikn-scaled K)
        acc[1][dt] = MFMA(af, bv, acc[1][dt]);    // M2
      }
    }
    if (kt + 1 < 8) {
      WRITEA(cur ^ 1);
      __syncthreads();
      cur ^= 1;
    }
  }

  float* outp = Mpart + ((size_t)(hb * 4 + ms)) * 8192;
#pragma unroll
  for (int mat = 0; mat < 2; mat++)
#pragma unroll
    for (int dt = 0; dt < 4; dt++) {
      int d = dt * 16 + lo;
#pragma unroll
      for (int rg = 0; rg < 4; rg++) {
        int j = mat * 64 + w * 16 + hi * 4 + rg;
        outp[j * 64 + d] = acc[mat][dt][rg];
      }
    }
#undef AK_
#undef AKH_
#undef BV_
}

// ---------------------------------------------------------------------------
// K3: reduceM_mlp_w — grid 16 (hb), 256 thr. Per hb:
//  ph0: MLP (wave 0) -> alpha/beta/gamma
//  ph1: reduce 4 Mpart splits -> Ms[128][65] f32 (rows 0-63 M1, 64-127 M2)
//  ph2: S2[d] = colsum(M2); ph3: M1b = a*M1, Cb = b*M2 - (g/4096)*S2 (bf16)
//  ph4: Wbig[b][dout][h*64+i] = Wo_h @ M1b^T ; [.. 512+..] = Wo_h @ Cb^T
// ---------------------------------------------------------------------------
__global__ __launch_bounds__(256) void reduceM_mlp_w(
    const float* __restrict__ Mpart, const float* __restrict__ qgp,
    const float* __restrict__ kgp, const float* __restrict__ w1,
    const float* __restrict__ b1, const float* __restrict__ lng,
    const float* __restrict__ lnb, const float* __restrict__ w2,
    const float* __restrict__ b2, const u16* __restrict__ Wo,
    u16* __restrict__ Wbig) {
  int hb = blockIdx.x;
  int h = hb >> 1, b = hb & 1;
  int tid = threadIdx.x, w = tid >> 6, l = tid & 63;
  int lo = l & 15, hi = l >> 4;

  __shared__ float abg[3];
  __shared__ float Ms[128][65];   // 33 KB
  __shared__ float S2s[64];
  __shared__ u16 M1b[64 * 72];
  __shared__ u16 Cb[64 * 72];
  __shared__ float qg[64], kg[64];

  // phase 0: MLP on wave 0
  if (tid < 64) {
    float s1 = 0.f, s2 = 0.f;
#pragma unroll
    for (int c = 0; c < 32; c++) {
      s1 += qgp[(c * 8 + h) * 64 + tid];
      s2 += kgp[(c * 8 + h) * 64 + tid];
    }
    qg[tid] = s1 * (1.f / 4096.f);
    kg[tid] = s2 * (1.f / 4096.f);
    float acc = b1[tid];
#pragma unroll 8
    for (int i = 0; i < 64; i++)
      acc += qg[i] * w1[tid * 128 + i] + kg[i] * w1[tid * 128 + 64 + i];
    float t1 = acc, t2 = acc * acc;
#pragma unroll
    for (int m = 1; m < 64; m <<= 1) { t1 += __shfl_xor(t1, m); t2 += __shfl_xor(t2, m); }
    float mean = t1 * (1.f / 64.f);
    float var = t2 * (1.f / 64.f) - mean * mean;
    float y = (acc - mean) * rsqrtf(var + 1e-5f) * lng[tid] + lnb[tid];
    float hid = fmaxf(y, 0.f);
    float t = hid * w2[tid];
#pragma unroll
    for (int m = 1; m < 64; m <<= 1) t += __shfl_xor(t, m);
    float wv = 1.f / (1.f + expf(-(t + b2[0])));
    if (tid == 0) { abg[0] = 1.f - wv; abg[1] = wv * (1.f / 64.f); abg[2] = wv; }
  }

  // phase 1: reduce 4 m-split partials
#pragma unroll
  for (int e = 0; e < 32; e++) {
    int idx = e * 256 + tid;
    int j = idx >> 6, d = idx & 63;
    float s = 0.f;
#pragma unroll
    for (int ms = 0; ms < 4; ms++)
      s += Mpart[((size_t)(hb * 4 + ms)) * 8192 + idx];
    Ms[j][d] = s;
  }
  __syncthreads();

  // phase 2: S2[d] = colsum over i of M2
  if (tid < 64) {
    float s = 0.f;
#pragma unroll
    for (int i = 0; i < 64; i++) s += Ms[64 + i][tid];
    S2s[tid] = s;
  }
  __syncthreads();

  // phase 3: bf16 B-operands (M1b[i][d], Cb[i][d], stride 72)
  float alpha = abg[0], beta = abg[1], g4 = abg[2] * (1.f / 4096.f);
#pragma unroll
  for (int e = 0; e < 16; e++) {
    int idx = e * 256 + tid;
    int i = idx >> 6, d = idx & 63;
    M1b[i * 72 + d] = f2bf(alpha * Ms[i][d]);
    Cb[i * 72 + d] = f2bf(beta * Ms[64 + i][d] - g4 * S2s[d]);
  }
  __syncthreads();

  // phase 4: Wbig build — wave w: dout rows [w*128, w*128+128)
  f32x4 zz = {0.f, 0.f, 0.f, 0.f};
  u16* Wb = Wbig + (size_t)b * 512 * 1024;
#pragma unroll
  for (int rf = 0; rf < 8; rf++) {
    int dbase = w * 128 + rf * 16;
    bf16x8 af[2];
#pragma unroll
    for (int kk = 0; kk < 2; kk++)
      af[kk] = *(const bf16x8*)&Wo[(size_t)(dbase + lo) * 512 + h * 64 + kk * 32 + hi * 8];
    f32x4 a1[4], a2[4];
#pragma unroll
    for (int cf = 0; cf < 4; cf++) { a1[cf] = zz; a2[cf] = zz; }
#pragma unroll
    for (int kk = 0; kk < 2; kk++)
#pragma unroll
      for (int cf = 0; cf < 4; cf++) {
        bf16x8 m1 = *(const bf16x8*)&M1b[(cf * 16 + lo) * 72 + kk * 32 + hi * 8];
        bf16x8 cb = *(const bf16x8*)&Cb[(cf * 16 + lo) * 72 + kk * 32 + hi * 8];
        a1[cf] = MFMA(af[kk], m1, a1[cf]);
        a2[cf] = MFMA(af[kk], cb, a2[cf]);
      }
#pragma unroll
    for (int cf = 0; cf < 4; cf++)
#pragma unroll
      for (int rg = 0; rg < 4; rg++) {
        int dout = dbase + hi * 4 + rg;
        int icol = cf * 16 + lo;
        Wb[(size_t)dout * 1024 + h * 64 + icol] = f2bf(a1[cf][rg]);
        Wb[(size_t)dout * 1024 + 512 + h * 64 + icol] = f2bf(a2[cf][rg]);
      }
  }
}

// ---------------------------------------------------------------------------
// K4: gemm_final — out = F0cat @ Wbig[b]^T + b_out (f32). K=1024, BK=64, dbuf.
// grid (32,4); b = blockIdx.x>=16.
// ---------------------------------------------------------------------------
__global__ __launch_bounds__(256) void gemm_final(const u16* __restrict__ A,
                                                  const u16* __restrict__ Wbig,
                                                  const float* __restrict__ bias,
                                                  float* __restrict__ Cout) {
  __shared__ u16 Al[2][128 * 64];
  __shared__ u16 Bl[2][128 * 64];
  int tm = blockIdx.x * 128, tn = blockIdx.y * 128;
  const u16* Bt = Wbig + (size_t)(tm >> 11) * 512 * 1024;
  int tid = threadIdx.x;
  int w = tid >> 6, l = tid & 63;
  int wr = w >> 1, wc = w & 1;
  int lo = l & 15, hi = l >> 4;

  f32x4 zz = {0.f, 0.f, 0.f, 0.f};
  f32x4 acc[4][4];
#pragma unroll
  for (int mi = 0; mi < 4; mi++)
#pragma unroll
    for (int ni = 0; ni < 4; ni++) acc[mi][ni] = zz;

  int rowA = 8 * w + (l >> 3);
  int sl = l & 7;

#pragma unroll
  for (int i = 0; i < 4; i++) {
    int rl = rowA + 32 * i;
    int sp = sl ^ (rl & 7);
    GLOAD16(A + (size_t)(tm + rl) * 1024 + sp * 8, (char*)Al[0] + w * 1024 + i * 4096);
    GLOAD16(Bt + (size_t)(tn + rl) * 1024 + sp * 8, (char*)Bl[0] + w * 1024 + i * 4096);
  }
  __syncthreads();

  int cur = 0;
  for (int kt = 0; kt < 16; ++kt) {
    if (kt + 1 < 16) {
      int nxt = cur ^ 1;
#pragma unroll
      for (int i = 0; i < 4; i++) {
        int rl = rowA + 32 * i;
        int sp = sl ^ (rl & 7);
        GLOAD16(A + (size_t)(tm + rl) * 1024 + (kt + 1) * 64 + sp * 8,
                (char*)Al[nxt] + w * 1024 + i * 4096);
        GLOAD16(Bt + (size_t)(tn + rl) * 1024 + (kt + 1) * 64 + sp * 8,
                (char*)Bl[nxt] + w * 1024 + i * 4096);
      }
    }
    const u16* Ac = Al[cur];
    const u16* Bc = Bl[cur];
#pragma unroll
    for (int kk = 0; kk < 2; kk++) {
      bf16x8 af[4], bfr[4];
#pragma unroll
      for (int mi = 0; mi < 4; mi++) {
        int row = wr * 64 + mi * 16 + lo;
        int slot = (hi + 4 * kk) ^ (row & 7);
        af[mi] = *(const bf16x8*)&Ac[row * 64 + slot * 8];
      }
#pragma unroll
      for (int ni = 0; ni < 4; ni++) {
        int row = wc * 64 + ni * 16 + lo;
        int slot = (hi + 4 * kk) ^ (row & 7);
        bfr[ni] = *(const bf16x8*)&Bc[row * 64 + slot * 8];
      }
#pragma unroll
      for (int mi = 0; mi < 4; mi++)
#pragma unroll
        for (int ni = 0; ni < 4; ni++)
          acc[mi][ni] = MFMA(af[mi], bfr[ni], acc[mi][ni]);
    }
    if (kt + 1 < 16) {
      __syncthreads();
      cur ^= 1;
    }
  }
#pragma unroll
  for (int mi = 0; mi < 4; mi++)
#pragma unroll
    for (int ni = 0; ni < 4; ni++) {
      int col = tn + wc * 64 + ni * 16 + lo;
      float bv = bias[col];
#pragma unroll
      for (int rg = 0; rg < 4; rg++) {
        int rowg = tm + wr * 64 + mi * 16 + hi * 4 + rg;
        Cout[(size_t)rowg * CD + col] = acc[mi][ni][rg] + bv;
      }
    }
}

// ---------------------------------------------------------------------------
extern "C" void kernel_launch(void* const* d_in, const int* in_sizes, int n_in,
                              void* d_out, int out_size, void* d_ws, size_t ws_size,
                              hipStream_t stream) {
  const float* q = (const float*)d_in[0];
  const float* k = (const float*)d_in[1];
  const float* v = (const float*)d_in[2];
  const float* ln_g = (const float*)d_in[3];
  const float* ln_b = (const float*)d_in[4];
  const float* W_in = (const float*)d_in[5];
  const float* wp_w1 = (const float*)d_in[6];
  const float* wp_b1 = (const float*)d_in[7];
  const float* wp_lng = (const float*)d_in[8];
  const float* wp_lnb = (const float*)d_in[9];
  const float* wp_w2 = (const float*)d_in[10];
  const float* wp_b2 = (const float*)d_in[11];
  const float* W_out = (const float*)d_in[12];
  const float* b_out = (const float*)d_in[13];

  char* ws = (char*)d_ws;
  u16* xln = (u16*)(ws + 0);              // 12,582,912 B  [3*4096][512]
  u16* F0cat = (u16*)(ws + 12582912);     // 8,388,608 B   [4096][1024]
  u16* Wi = (u16*)(ws + 20971520);        // 524,288 B
  u16* Wo = (u16*)(ws + 21495808);        // 524,288 B
  u16* fkT = (u16*)(ws + 22020096);       // 4,194,304 B   [HB][64][2048]
  u16* fvT = (u16*)(ws + 26214400);       // 4,194,304 B
  float* ikn = (float*)(ws + 30408704);   // 131,072 B
  float* qgp = (float*)(ws + 30539776);   // 65,536 B
  float* kgp = (float*)(ws + 30605312);   // 65,536 B
  u16* Wbig = (u16*)(ws + 30670848);      // 2,097,152 B   [2][512][1024] bf16
  float* Mpart = (float*)(ws + 32768000); // 2,097,152 B   [64][128][64] f32

  ln_convw_kernel<<<13312, 256, 0, stream>>>(q, k, v, ln_g, ln_b, xln,
                                             W_in, W_out, Wi, Wo);
  gemm1<<<dim3(96, 4), 256, 0, stream>>>(xln, Wi, F0cat, ikn, qgp, kgp, fkT, fvT);
  gemm_M<<<64, 256, 0, stream>>>(fkT, fvT, ikn, Mpart);
  reduceM_mlp_w<<<16, 256, 0, stream>>>(Mpart, qgp, kgp, wp_w1, wp_b1,
                                        wp_lng, wp_lnb, wp_w2, wp_b2, Wo, Wbig);
  gemm_final<<<dim3(32, 4), 256, 0, stream>>>(F0cat, Wbig, b_out, (float*)d_out);
}

// Round 14
// 62.521 us; speedup vs baseline: 1.5739x; 1.1934x over previous
//
#include <hip/hip_runtime.h>
#include <stdint.h>

// Problem constants
#define CH 8      // heads
#define CDH 64    // dim head
#define CB 2      // batch
#define CN 2048   // seq
#define CD 512    // model dim

typedef float f32x4 __attribute__((ext_vector_type(4)));
typedef __bf16 bf16x8 __attribute__((ext_vector_type(8)));
typedef unsigned short u16;

#define MFMA(a, b, c) __builtin_amdgcn_mfma_f32_16x16x32_bf16((a), (b), (c), 0, 0, 0)
#define GLOAD16(g, l)                                                              \
  __builtin_amdgcn_global_load_lds((const __attribute__((address_space(1))) void*)(g), \
                                   (__attribute__((address_space(3))) void*)(l), 16, 0, 0)

__device__ __forceinline__ u16 f2bf(float f) {
  union { float f; unsigned u; } c; c.f = f;
  return (u16)((c.u + 0x7FFFu + ((c.u >> 16) & 1u)) >> 16);
}
__device__ __forceinline__ float bf2f(u16 h) {
  union { unsigned u; float f; } c; c.u = ((unsigned)h) << 16;
  return c.f;
}

// ---------------------------------------------------------------------------
// K0: LayerNorm for q,k,v -> xln bf16 [3*4096][512]; tail blocks convert W
// grid 13312 = 12288 LN + 1024 conv
// ---------------------------------------------------------------------------
__global__ __launch_bounds__(256) void ln_convw_kernel(const float* __restrict__ q,
                                                       const float* __restrict__ k,
                                                       const float* __restrict__ v,
                                                       const float* __restrict__ g,
                                                       const float* __restrict__ bb,
                                                       u16* __restrict__ xln,
                                                       const float* __restrict__ wi_f,
                                                       const float* __restrict__ wo_f,
                                                       u16* __restrict__ wi,
                                                       u16* __restrict__ wo) {
  int row = blockIdx.x;
  int tid = threadIdx.x;
  if (row >= 12288) {
    int i = (row - 12288) * 256 + tid;   // < 262144
    wi[i] = f2bf(wi_f[i]);
    wo[i] = f2bf(wo_f[i]);
    return;
  }
  int t = row >> 12;
  int rr = row & 4095;
  const float* src = (t == 0 ? q : (t == 1 ? k : v)) + (size_t)rr * CD;
  float x0 = src[tid], x1 = src[tid + 256];
  float s = x0 + x1, s2 = x0 * x0 + x1 * x1;
#pragma unroll
  for (int m = 1; m < 64; m <<= 1) { s += __shfl_xor(s, m); s2 += __shfl_xor(s2, m); }
  __shared__ float red[8];
  int w = tid >> 6;
  if ((tid & 63) == 0) { red[w] = s; red[4 + w] = s2; }
  __syncthreads();
  s = red[0] + red[1] + red[2] + red[3];
  s2 = red[4] + red[5] + red[6] + red[7];
  float mean = s * (1.f / 512.f);
  float var = s2 * (1.f / 512.f) - mean * mean;
  float rstd = rsqrtf(var + 1e-5f);
  u16* dst = xln + (size_t)row * CD;
  dst[tid]       = f2bf((x0 - mean) * rstd * g[tid] + bb[tid]);
  dst[tid + 256] = f2bf((x1 - mean) * rstd * g[tid + 256] + bb[tid + 256]);
}

// ---------------------------------------------------------------------------
// K1: gemm1 = xln @ Wi^T, BM=BN=128, BK=64, dbuf.
// tblk<32 (q rows): write F0 + iqn/qgp stats.
// tblk 32..63 (k): transpose to fkT + ikn + kgp; no C write.
// tblk 64..95 (v): transpose to fvT; no C write.
// ---------------------------------------------------------------------------
__global__ __launch_bounds__(256) void gemm1(const u16* __restrict__ A,
                                             const u16* __restrict__ Bt,
                                             u16* __restrict__ F0,
                                             float* __restrict__ iqn,
                                             float* __restrict__ ikn,
                                             float* __restrict__ qgp,
                                             float* __restrict__ kgp,
                                             u16* __restrict__ fkT,
                                             u16* __restrict__ fvT) {
  __shared__ u16 S[4][8192];
#define AL_(s) (S[s])
#define BL_(s) (S[2 + (s)])
  int tm = blockIdx.x * 128, tn = blockIdx.y * 128;
  int tid = threadIdx.x;
  int w = tid >> 6, l = tid & 63;
  int wr = w >> 1, wc = w & 1;
  int lo = l & 15, hi = l >> 4;

  f32x4 zz = {0.f, 0.f, 0.f, 0.f};
  f32x4 acc[4][4];
#pragma unroll
  for (int mi = 0; mi < 4; mi++)
#pragma unroll
    for (int ni = 0; ni < 4; ni++) acc[mi][ni] = zz;

  int rowA = 8 * w + (l >> 3);
  int sl = l & 7;

#pragma unroll
  for (int i = 0; i < 4; i++) {
    int rl = rowA + 32 * i;
    int sp = sl ^ (rl & 7);
    GLOAD16(A + (size_t)(tm + rl) * CD + sp * 8, (char*)AL_(0) + w * 1024 + i * 4096);
    GLOAD16(Bt + (size_t)(tn + rl) * CD + sp * 8, (char*)BL_(0) + w * 1024 + i * 4096);
  }
  __syncthreads();

  int cur = 0;
  for (int kt = 0; kt < 8; ++kt) {
    if (kt + 1 < 8) {
      int nxt = cur ^ 1;
#pragma unroll
      for (int i = 0; i < 4; i++) {
        int rl = rowA + 32 * i;
        int sp = sl ^ (rl & 7);
        GLOAD16(A + (size_t)(tm + rl) * CD + (kt + 1) * 64 + sp * 8,
                (char*)AL_(nxt) + w * 1024 + i * 4096);
        GLOAD16(Bt + (size_t)(tn + rl) * CD + (kt + 1) * 64 + sp * 8,
                (char*)BL_(nxt) + w * 1024 + i * 4096);
      }
    }
    const u16* Ac = AL_(cur);
    const u16* Bc = BL_(cur);
#pragma unroll
    for (int kk = 0; kk < 2; kk++) {
      bf16x8 af[4], bfr[4];
#pragma unroll
      for (int mi = 0; mi < 4; mi++) {
        int row = wr * 64 + mi * 16 + lo;
        int slot = (hi + 4 * kk) ^ (row & 7);
        af[mi] = *(const bf16x8*)&Ac[row * 64 + slot * 8];
      }
#pragma unroll
      for (int ni = 0; ni < 4; ni++) {
        int row = wc * 64 + ni * 16 + lo;
        int slot = (hi + 4 * kk) ^ (row & 7);
        bfr[ni] = *(const bf16x8*)&Bc[row * 64 + slot * 8];
      }
#pragma unroll
      for (int mi = 0; mi < 4; mi++)
#pragma unroll
        for (int ni = 0; ni < 4; ni++)
          acc[mi][ni] = MFMA(af[mi], bfr[ni], acc[mi][ni]);
    }
    if (kt + 1 < 8) {
      __syncthreads();
      cur ^= 1;
    }
  }

  int tblk = blockIdx.x;
  int h = blockIdx.y * 2 + wc;
  if (tblk < 32) {
    // ---- q rows: iqn + qgp stats, then C write (F0) ----
#pragma unroll
    for (int mi = 0; mi < 4; mi++)
#pragma unroll
      for (int rg = 0; rg < 4; rg++) {
        float s2 = 0.f;
#pragma unroll
        for (int ni = 0; ni < 4; ni++) {
          float vv = acc[mi][ni][rg];
          s2 += vv * vv;
        }
#pragma unroll
        for (int m = 1; m < 16; m <<= 1) s2 += __shfl_xor(s2, m);
        if (lo == 0) {
          int rloc = tm + wr * 64 + mi * 16 + hi * 4 + rg;
          int b = rloc >> 11, n = rloc & 2047;
          iqn[((size_t)h * 2 + b) * CN + n] = rsqrtf(s2);
        }
      }
    float cs[4];
#pragma unroll
    for (int ni = 0; ni < 4; ni++) {
      float s = 0.f;
#pragma unroll
      for (int mi = 0; mi < 4; mi++)
#pragma unroll
        for (int rg = 0; rg < 4; rg++) s += acc[mi][ni][rg];
      s += __shfl_xor(s, 16);
      s += __shfl_xor(s, 32);
      cs[ni] = s;
    }
    __syncthreads();
    float* redl = (float*)&S[0][0];
    if (hi == 0)
#pragma unroll
      for (int ni = 0; ni < 4; ni++) redl[((wr * 2 + wc) * 4 + ni) * 16 + lo] = cs[ni];
    __syncthreads();
    if (wr == 0 && hi == 0) {
#pragma unroll
      for (int ni = 0; ni < 4; ni++) {
        float vsum = redl[((0 * 2 + wc) * 4 + ni) * 16 + lo] +
                     redl[((1 * 2 + wc) * 4 + ni) * 16 + lo];
        qgp[(tblk * 8 + h) * 64 + ni * 16 + lo] = vsum;
      }
    }
#pragma unroll
    for (int mi = 0; mi < 4; mi++)
#pragma unroll
      for (int ni = 0; ni < 4; ni++) {
        int gcol = tn + wc * 64 + ni * 16 + lo;
#pragma unroll
        for (int rg = 0; rg < 4; rg++) {
          int rowg = tm + wr * 64 + mi * 16 + hi * 4 + rg;
          F0[(size_t)rowg * CD + gcol] = f2bf(acc[mi][ni][rg]);
        }
      }
  } else {
    // ---- k/v rows: transpose to fkT/fvT; k also ikn + kgp ----
    bool isk = tblk < 64;
    u16* dstT = isk ? fkT : fvT;
    int rloc0 = tm - (isk ? 4096 : 8192);
    int bb2 = rloc0 >> 11, n0 = rloc0 & 2047;
    float csk[4];
    if (isk) {
#pragma unroll
      for (int mi = 0; mi < 4; mi++)
#pragma unroll
        for (int rg = 0; rg < 4; rg++) {
          float s2 = 0.f;
#pragma unroll
          for (int ni = 0; ni < 4; ni++) {
            float vv = acc[mi][ni][rg];
            s2 += vv * vv;
          }
#pragma unroll
          for (int m = 1; m < 16; m <<= 1) s2 += __shfl_xor(s2, m);
          if (lo == 0) {
            int n = n0 + wr * 64 + mi * 16 + hi * 4 + rg;
            ikn[((size_t)h * 2 + bb2) * CN + n] = rsqrtf(s2);
          }
        }
#pragma unroll
      for (int ni = 0; ni < 4; ni++) {
        float s = 0.f;
#pragma unroll
        for (int mi = 0; mi < 4; mi++)
#pragma unroll
          for (int rg = 0; rg < 4; rg++) s += acc[mi][ni][rg];
        s += __shfl_xor(s, 16);
        s += __shfl_xor(s, 32);
        csk[ni] = s;
      }
    }
    __syncthreads();
    u16* Sf = &S[0][0];
    int reg = wc * 2 + wr;
#pragma unroll
    for (int mi = 0; mi < 4; mi++)
#pragma unroll
      for (int ni = 0; ni < 4; ni++) {
        int d = ni * 16 + lo;
        int m0 = mi * 16 + hi * 4;
        u16 t4[4];
#pragma unroll
        for (int rg = 0; rg < 4; rg++) t4[rg] = f2bf(acc[mi][ni][rg]);
        int off = (reg * 64 + d) * 64 + (m0 ^ ((d & 7) << 3));
        *(uint2*)&Sf[off] = *(const uint2*)t4;
      }
    __syncthreads();
    {
      int head = tid >> 7, c = tid & 127;
      int hg = blockIdx.y * 2 + head;
      size_t base = ((size_t)(hg * 2 + bb2)) * 64 * CN;
#pragma unroll
      for (int p = 0; p < 8; p++) {
        int flat = p * 128 + c;
        int d = flat >> 4, mc = flat & 15;
        int wr2 = mc >> 3, m64 = (mc & 7) * 8;
        int off = ((head * 2 + wr2) * 64 + d) * 64 + (m64 ^ ((d & 7) << 3));
        bf16x8 vv = *(const bf16x8*)&Sf[off];
        *(bf16x8*)&dstT[base + (size_t)d * CN + n0 + mc * 8] = vv;
      }
    }
    if (isk) {
      __syncthreads();
      float* redl = (float*)&S[0][0];
      if (hi == 0)
#pragma unroll
        for (int ni = 0; ni < 4; ni++) redl[((wr * 2 + wc) * 4 + ni) * 16 + lo] = csk[ni];
      __syncthreads();
      if (wr == 0 && hi == 0) {
#pragma unroll
        for (int ni = 0; ni < 4; ni++) {
          float vsum = redl[((0 * 2 + wc) * 4 + ni) * 16 + lo] +
                       redl[((1 * 2 + wc) * 4 + ni) * 16 + lo];
          kgp[((tblk - 32) * 8 + h) * 64 + ni * 16 + lo] = vsum;
        }
      }
    }
  }
#undef AL_
#undef BL_
}

// ---------------------------------------------------------------------------
// K2: gemm_M — per (h,b): M1 = (K*ikn)^T V, M2 = K^T V (64x64 each), m-split 4.
// grid 64 (hb:4 low | ms:2), 256 threads.
// ---------------------------------------------------------------------------
__global__ __launch_bounds__(256) void gemm_M(const u16* __restrict__ fkT,
                                              const u16* __restrict__ fvT,
                                              const float* __restrict__ ikn,
                                              float* __restrict__ Mpart) {
  int bid = blockIdx.x;
  int hb = bid & 15, ms = bid >> 4;   // ms in [0,4)
  int tid = threadIdx.x, w = tid >> 6, l = tid & 63;
  int lo = l & 15, hi = l >> 4;

  __shared__ u16 GM[6][4096];   // Ak[2], Akh[2], Bv[2]
#define AK_(s) (GM[s])
#define AKH_(s) (GM[2 + (s)])
#define BV_(s) (GM[4 + (s)])

  const u16* Ab = fkT + (size_t)hb * 64 * CN;
  const u16* Vb = fvT + (size_t)hb * 64 * CN;
  const float* ikb = ikn + (size_t)hb * CN;

  f32x4 zz = {0.f, 0.f, 0.f, 0.f};
  f32x4 acc[2][4];
#pragma unroll
  for (int mat = 0; mat < 2; mat++)
#pragma unroll
    for (int dt = 0; dt < 4; dt++) acc[mat][dt] = zz;

  int rls = 8 * w + (l >> 3);
  int sls = l & 7;

  bf16x8 areg[2];
  f32x4 ikreg[2][2];

  auto STAGEGL = [&](int kt, int slot) {
    int mc = ms * 512 + kt * 64;
#pragma unroll
    for (int i = 0; i < 2; i++) {
      int row = rls + 32 * i;
      int sp = sls ^ (row & 7);
      GLOAD16(Ab + (size_t)row * CN + mc + sp * 8, (char*)AK_(slot) + w * 1024 + i * 4096);
      GLOAD16(Vb + (size_t)row * CN + mc + sp * 8, (char*)BV_(slot) + w * 1024 + i * 4096);
    }
  };
  auto LOADA = [&](int kt) {
    int mc = ms * 512 + kt * 64;
#pragma unroll
    for (int i = 0; i < 2; i++) {
      int row = rls + 32 * i;
      int sp = sls ^ (row & 7);
      areg[i] = *(const bf16x8*)&Ab[(size_t)row * CN + mc + sp * 8];
      ikreg[i][0] = *(const f32x4*)&ikb[mc + sp * 8];
      ikreg[i][1] = *(const f32x4*)&ikb[mc + sp * 8 + 4];
    }
  };
  auto WRITEA = [&](int slot) {
#pragma unroll
    for (int i = 0; i < 2; i++) {
      u16 outp[8];
#pragma unroll
      for (int j = 0; j < 4; j++) outp[j] = f2bf((float)areg[i][j] * ikreg[i][0][j]);
#pragma unroll
      for (int j = 0; j < 4; j++) outp[4 + j] = f2bf((float)areg[i][4 + j] * ikreg[i][1][j]);
      *(bf16x8*)((char*)AKH_(slot) + w * 1024 + i * 4096 + l * 16) = *(const bf16x8*)outp;
    }
  };

  LOADA(0);
  STAGEGL(0, 0);
  WRITEA(0);
  __syncthreads();

  int cur = 0;
  for (int kt = 0; kt < 8; ++kt) {
    if (kt + 1 < 8) {
      LOADA(kt + 1);
      STAGEGL(kt + 1, cur ^ 1);
    }
#pragma unroll
    for (int kk = 0; kk < 2; kk++) {
      int arow = w * 16 + lo;
      int aslot = (hi + 4 * kk) ^ (arow & 7);
      bf16x8 af = *(const bf16x8*)&AK_(cur)[arow * 64 + aslot * 8];
      bf16x8 afh = *(const bf16x8*)&AKH_(cur)[arow * 64 + aslot * 8];
#pragma unroll
      for (int dt = 0; dt < 4; dt++) {
        int brow = dt * 16 + lo;
        int bslot = (hi + 4 * kk) ^ (brow & 7);
        bf16x8 bv = *(const bf16x8*)&BV_(cur)[brow * 64 + bslot * 8];
        acc[0][dt] = MFMA(afh, bv, acc[0][dt]);   // M1 (ikn-scaled K)
        acc[1][dt] = MFMA(af, bv, acc[1][dt]);    // M2
      }
    }
    if (kt + 1 < 8) {
      WRITEA(cur ^ 1);
      __syncthreads();
      cur ^= 1;
    }
  }

  float* outp = Mpart + ((size_t)(hb * 4 + ms)) * 8192;
#pragma unroll
  for (int mat = 0; mat < 2; mat++)
#pragma unroll
    for (int dt = 0; dt < 4; dt++) {
      int d = dt * 16 + lo;
#pragma unroll
      for (int rg = 0; rg < 4; rg++) {
        int j = mat * 64 + w * 16 + hi * 4 + rg;
        outp[j * 64 + d] = acc[mat][dt][rg];
      }
    }
#undef AK_
#undef AKH_
#undef BV_
}

// ---------------------------------------------------------------------------
// K3: reduceM_mlp — per hb: MLP + reduce 4 m-split partials, fold rank-1,
// write Bmat[hb][jrow][icol] bf16.  grid 16, 256 thr.
// ---------------------------------------------------------------------------
__global__ __launch_bounds__(256) void reduceM_mlp(const float* __restrict__ Mpart,
                                                   const float* __restrict__ qgp,
                                                   const float* __restrict__ kgp,
                                                   const float* __restrict__ w1,
                                                   const float* __restrict__ b1,
                                                   const float* __restrict__ lng,
                                                   const float* __restrict__ lnb,
                                                   const float* __restrict__ w2,
                                                   const float* __restrict__ b2,
                                                   u16* __restrict__ Bmat) {
  int hb = blockIdx.x;
  int h = hb >> 1;
  int tid = threadIdx.x;
  __shared__ float qg[64], kg[64], abg[3];
  if (tid < 64) {
    float s1 = 0.f, s2 = 0.f;
#pragma unroll
    for (int c = 0; c < 32; c++) {
      s1 += qgp[(c * 8 + h) * 64 + tid];
      s2 += kgp[(c * 8 + h) * 64 + tid];
    }
    qg[tid] = s1 * (1.f / 4096.f);
    kg[tid] = s2 * (1.f / 4096.f);
    float acc = b1[tid];
#pragma unroll 8
    for (int i = 0; i < 64; i++)
      acc += qg[i] * w1[tid * 128 + i] + kg[i] * w1[tid * 128 + 64 + i];
    float t1 = acc, t2 = acc * acc;
#pragma unroll
    for (int m = 1; m < 64; m <<= 1) { t1 += __shfl_xor(t1, m); t2 += __shfl_xor(t2, m); }
    float mean = t1 * (1.f / 64.f);
    float var = t2 * (1.f / 64.f) - mean * mean;
    float y = (acc - mean) * rsqrtf(var + 1e-5f) * lng[tid] + lnb[tid];
    float hid = fmaxf(y, 0.f);
    float t = hid * w2[tid];
#pragma unroll
    for (int m = 1; m < 64; m <<= 1) t += __shfl_xor(t, m);
    float wv = 1.f / (1.f + expf(-(t + b2[0])));
    if (tid == 0) { abg[0] = 1.f - wv; abg[1] = wv * (1.f / 64.f); abg[2] = wv; }
  }
  __syncthreads();
  float alpha = abg[0], beta = abg[1], gamma = abg[2];

  __shared__ float Ms[128 * 65];
  __shared__ float S2s[64];
#pragma unroll
  for (int e = 0; e < 32; e++) {
    int idx = e * 256 + tid;
    int j = idx >> 6, d = idx & 63;
    float s = 0.f;
#pragma unroll
    for (int ms = 0; ms < 4; ms++)
      s += Mpart[((size_t)(hb * 4 + ms)) * 8192 + idx];
    Ms[j * 65 + d] = s;
  }
  __syncthreads();
  if (tid < 64) {
    float s = 0.f;
#pragma unroll
    for (int i = 0; i < 64; i++) s += Ms[(64 + i) * 65 + tid];
    S2s[tid] = s;
  }
  __syncthreads();
#pragma unroll
  for (int e = 0; e < 32; e++) {
    int idx = e * 256 + tid;
    int jr = idx >> 6, ic = idx & 63;
    float v;
    if (jr < 64) v = alpha * Ms[ic * 65 + jr];
    else {
      int d = jr - 64;
      v = beta * Ms[(64 + ic) * 65 + d] - (gamma * (1.f / 4096.f)) * S2s[d];
    }
    Bmat[(size_t)hb * 8192 + idx] = f2bf(v);
  }
}

// ---------------------------------------------------------------------------
// K4: gemm_out — out[n] = iqn[n]*(fq@aM1) + fq@(bM2 - rank1)  -> A2 bf16.
// grid 256 (hb*16+qt), 256 threads (4 waves), no LDS, no barriers.
// ---------------------------------------------------------------------------
__global__ __launch_bounds__(256) void gemm_out(const u16* __restrict__ F0,
                                                const u16* __restrict__ Bmat,
                                                const float* __restrict__ iqn,
                                                u16* __restrict__ A2) {
  int bid = blockIdx.x;
  int hb = bid >> 4, qt = bid & 15;
  int b = hb & 1, h = hb >> 1;
  int tid = threadIdx.x, w = tid >> 6, l = tid & 63;
  int lo = l & 15, hi = l >> 4;
  int qbase = qt * 128;

  const u16* Bm = Bmat + (size_t)hb * 8192;
  bf16x8 bm[8][2];
#pragma unroll
  for (int jt = 0; jt < 8; jt++)
#pragma unroll
    for (int kk = 0; kk < 2; kk++)
      bm[jt][kk] = *(const bf16x8*)&Bm[(jt * 16 + lo) * 64 + hi * 8 + kk * 32];

  f32x4 zz = {0.f, 0.f, 0.f, 0.f};
  f32x4 acc[2][8];
#pragma unroll
  for (int f = 0; f < 2; f++)
#pragma unroll
    for (int jt = 0; jt < 8; jt++) acc[f][jt] = zz;

#pragma unroll
  for (int f = 0; f < 2; f++) {
    const u16* qp = F0 + ((size_t)(b * CN + qbase + w * 32 + f * 16 + lo)) * CD +
                    h * 64 + hi * 8;
    bf16x8 a0 = *(const bf16x8*)qp;
    bf16x8 a1 = *(const bf16x8*)(qp + 32);
#pragma unroll
    for (int jt = 0; jt < 8; jt++) {
      acc[f][jt] = MFMA(a0, bm[jt][0], acc[f][jt]);
      acc[f][jt] = MFMA(a1, bm[jt][1], acc[f][jt]);
    }
  }

  const float* iqn_hb = iqn + (size_t)hb * CN;
#pragma unroll
  for (int f = 0; f < 2; f++) {
    float iqv[4];
    int nb = qbase + w * 32 + f * 16 + hi * 4;
#pragma unroll
    for (int rg = 0; rg < 4; rg++) iqv[rg] = iqn_hb[nb + rg];
#pragma unroll
    for (int jt = 0; jt < 4; jt++) {
      int d = jt * 16 + lo;
#pragma unroll
      for (int rg = 0; rg < 4; rg++) {
        float vout = iqv[rg] * acc[f][jt][rg] + acc[f][jt + 4][rg];
        int n = nb + rg;
        A2[((size_t)(b * CN + n)) * CD + h * 64 + d] = f2bf(vout);
      }
    }
  }
}

// ---------------------------------------------------------------------------
// K5: gemm2 — out = A2 @ Wo^T + b_out (f32). K=512, BK=64, dbuf. grid (32,4).
// ---------------------------------------------------------------------------
__global__ __launch_bounds__(256) void gemm2(const u16* __restrict__ A,
                                             const u16* __restrict__ Bt,
                                             const float* __restrict__ bias,
                                             float* __restrict__ Cout) {
  __shared__ u16 Al[2][128 * 64];
  __shared__ u16 Bl[2][128 * 64];
  int tm = blockIdx.x * 128, tn = blockIdx.y * 128;
  int tid = threadIdx.x;
  int w = tid >> 6, l = tid & 63;
  int wr = w >> 1, wc = w & 1;
  int lo = l & 15, hi = l >> 4;

  f32x4 zz = {0.f, 0.f, 0.f, 0.f};
  f32x4 acc[4][4];
#pragma unroll
  for (int mi = 0; mi < 4; mi++)
#pragma unroll
    for (int ni = 0; ni < 4; ni++) acc[mi][ni] = zz;

  int rowA = 8 * w + (l >> 3);
  int sl = l & 7;

#pragma unroll
  for (int i = 0; i < 4; i++) {
    int rl = rowA + 32 * i;
    int sp = sl ^ (rl & 7);
    GLOAD16(A + (size_t)(tm + rl) * CD + sp * 8, (char*)Al[0] + w * 1024 + i * 4096);
    GLOAD16(Bt + (size_t)(tn + rl) * CD + sp * 8, (char*)Bl[0] + w * 1024 + i * 4096);
  }
  __syncthreads();

  int cur = 0;
  for (int kt = 0; kt < 8; ++kt) {
    if (kt + 1 < 8) {
      int nxt = cur ^ 1;
#pragma unroll
      for (int i = 0; i < 4; i++) {
        int rl = rowA + 32 * i;
        int sp = sl ^ (rl & 7);
        GLOAD16(A + (size_t)(tm + rl) * CD + (kt + 1) * 64 + sp * 8,
                (char*)Al[nxt] + w * 1024 + i * 4096);
        GLOAD16(Bt + (size_t)(tn + rl) * CD + (kt + 1) * 64 + sp * 8,
                (char*)Bl[nxt] + w * 1024 + i * 4096);
      }
    }
    const u16* Ac = Al[cur];
    const u16* Bc = Bl[cur];
#pragma unroll
    for (int kk = 0; kk < 2; kk++) {
      bf16x8 af[4], bfr[4];
#pragma unroll
      for (int mi = 0; mi < 4; mi++) {
        int row = wr * 64 + mi * 16 + lo;
        int slot = (hi + 4 * kk) ^ (row & 7);
        af[mi] = *(const bf16x8*)&Ac[row * 64 + slot * 8];
      }
#pragma unroll
      for (int ni = 0; ni < 4; ni++) {
        int row = wc * 64 + ni * 16 + lo;
        int slot = (hi + 4 * kk) ^ (row & 7);
        bfr[ni] = *(const bf16x8*)&Bc[row * 64 + slot * 8];
      }
#pragma unroll
      for (int mi = 0; mi < 4; mi++)
#pragma unroll
        for (int ni = 0; ni < 4; ni++)
          acc[mi][ni] = MFMA(af[mi], bfr[ni], acc[mi][ni]);
    }
    if (kt + 1 < 8) {
      __syncthreads();
      cur ^= 1;
    }
  }
#pragma unroll
  for (int mi = 0; mi < 4; mi++)
#pragma unroll
    for (int ni = 0; ni < 4; ni++) {
      int col = tn + wc * 64 + ni * 16 + lo;
      float bv = bias[col];
#pragma unroll
      for (int rg = 0; rg < 4; rg++) {
        int rowg = tm + wr * 64 + mi * 16 + hi * 4 + rg;
        Cout[(size_t)rowg * CD + col] = acc[mi][ni][rg] + bv;
      }
    }
}

// ---------------------------------------------------------------------------
extern "C" void kernel_launch(void* const* d_in, const int* in_sizes, int n_in,
                              void* d_out, int out_size, void* d_ws, size_t ws_size,
                              hipStream_t stream) {
  const float* q = (const float*)d_in[0];
  const float* k = (const float*)d_in[1];
  const float* v = (const float*)d_in[2];
  const float* ln_g = (const float*)d_in[3];
  const float* ln_b = (const float*)d_in[4];
  const float* W_in = (const float*)d_in[5];
  const float* wp_w1 = (const float*)d_in[6];
  const float* wp_b1 = (const float*)d_in[7];
  const float* wp_lng = (const float*)d_in[8];
  const float* wp_lnb = (const float*)d_in[9];
  const float* wp_w2 = (const float*)d_in[10];
  const float* wp_b2 = (const float*)d_in[11];
  const float* W_out = (const float*)d_in[12];
  const float* b_out = (const float*)d_in[13];

  char* ws = (char*)d_ws;
  u16* xln = (u16*)(ws + 0);              // 12,582,912 B  [3*4096][512]
  u16* F0 = (u16*)(ws + 12582912);        // 4,194,304 B   [B*N][512] (q proj)
  u16* Wi = (u16*)(ws + 16777216);        // 524,288 B
  u16* Wo = (u16*)(ws + 17301504);        // 524,288 B
  u16* fkT = (u16*)(ws + 17825792);       // 4,194,304 B   [HB][64][2048]
  u16* fvT = (u16*)(ws + 22020096);       // 4,194,304 B
  u16* A2 = (u16*)(ws + 26214400);        // 4,194,304 B   [B][N][512]
  float* iqn = (float*)(ws + 30408704);   // 131,072 B
  float* ikn = (float*)(ws + 30539776);   // 131,072 B
  float* qgp = (float*)(ws + 30670848);   // 65,536 B
  float* kgp = (float*)(ws + 30736384);   // 65,536 B
  float* Mpart = (float*)(ws + 30801920); // 2,097,152 B   [64][128][64] f32
  u16* Bmat = (u16*)(ws + 32899072);      // 262,144 B     [16][128][64] bf16

  ln_convw_kernel<<<13312, 256, 0, stream>>>(q, k, v, ln_g, ln_b, xln,
                                             W_in, W_out, Wi, Wo);
  gemm1<<<dim3(96, 4), 256, 0, stream>>>(xln, Wi, F0, iqn, ikn, qgp, kgp, fkT, fvT);
  gemm_M<<<64, 256, 0, stream>>>(fkT, fvT, ikn, Mpart);
  reduceM_mlp<<<16, 256, 0, stream>>>(Mpart, qgp, kgp, wp_w1, wp_b1,
                                      wp_lng, wp_lnb, wp_w2, wp_b2, Bmat);
  gemm_out<<<256, 256, 0, stream>>>(F0, Bmat, iqn, A2);
  gemm2<<<dim3(32, 4), 256, 0, stream>>>(A2, Wo, b_out, (float*)d_out);
}